// Round 9
// baseline (14951.784 us; speedup 1.0000x reference)
//
#include <hip/hip_runtime.h>

// LSTMPredictor: B=32,T=512,H=128,L=5,IN=1,OUT=16,future=18 -> one 514-step scan.
// R9 MFMA redesign: 10 WGs = 5 layers x 2 batch-halves (M=16 batches each), 512 thr.
// gates[16,512] = A[16,256] @ Wcat^T via mfma_f32_16x16x32_f16; Wcat=[Whh|Wih] f16
// B-frags PERMANENTLY in 128 VGPRs (each weight feeds 16 batches/step -> kills the
// R2-R8 LDS-pipe bound of 1 LDS read per 2 FLOP). A (h own|up, f16) in LDS dbuf.
// Gates f32 through LDS (f16 gates would cost ~4e-3 err). Chunked sc1 ring transport.

typedef _Float16 v8h __attribute__((ext_vector_type(8)));
typedef _Float16 h4v __attribute__((ext_vector_type(4)));
typedef float f4 __attribute__((ext_vector_type(4)));

#define RING 16
#define TAIL 504
#define GUARD (1<<16)

#define FLAGL_OFF   0                 // int flagL[2*5][64]
#define FCFLAG_OFF  (64*1024)        // int fcflag[2][64]
#define FCOUT_OFF   (128*1024)       // float fcout[2][2][16]
#define RING_OFF    (256*1024)       // f16 ring[8 edges][16 slots][16 m][128 r] = 512KB
#define WCAT_OFF    (2*1024*1024)    // f16 Wcat[5][512][256] = 1.25MB
#define BIASC_OFF   (3*1024*1024 + 512*1024)  // float biasC[5][512]

#define AGENT __HIP_MEMORY_SCOPE_AGENT
#define LD(p)    __hip_atomic_load((p),  __ATOMIC_RELAXED, AGENT)
#define ST(p,v)  __hip_atomic_store((p), (v), __ATOMIC_RELAXED, AGENT)
#define LD64(p)  __hip_atomic_load((const unsigned long long*)(p), __ATOMIC_RELAXED, AGENT)
#define ST64(p,v) __hip_atomic_store((unsigned long long*)(p), (v), __ATOMIC_RELAXED, AGENT)

union HU { unsigned long long u; h4v v; };

__device__ __forceinline__ void bar_lgkm() {
    asm volatile("s_waitcnt lgkmcnt(0)\n\ts_barrier" ::: "memory");
}
__device__ __forceinline__ void drain_vm() {
    asm volatile("s_waitcnt vmcnt(0)" ::: "memory");
}
__device__ __forceinline__ float sigm(float x)   { return 1.f / (1.f + __expf(-x)); }
__device__ __forceinline__ float tanh_f(float x) { return 2.f / (1.f + __expf(-2.f * x)) - 1.f; }

// -------- init: zero flags, build Wcat f16 [5][512][256] and biasC --------
__global__ void lstm_init(const float* __restrict__ WihR, const float* __restrict__ Whh,
                          const float* __restrict__ bih,  const float* __restrict__ bhh,
                          char* __restrict__ ws)
{
    int idx = blockIdx.x * blockDim.x + threadIdx.x;
    int stride = gridDim.x * blockDim.x;
    int* wsi = (int*)ws;
    for (int i = idx; i < 65536; i += stride) wsi[i] = 0;   // flags + fcout (256KB)

    _Float16* WC = (_Float16*)(ws + WCAT_OFF);   // Wcat[l][n][k]: k<128 Whh, k>=128 Wih
    for (int i = idx; i < 5*512*256; i += stride) {
        int k = i & 255, n = (i >> 8) & 511, l = i >> 17;
        float v = (k < 128) ? Whh[(l*512 + n)*128 + k]
                            : (l > 0 ? WihR[((l-1)*512 + n)*128 + (k-128)] : 0.f);
        WC[i] = (_Float16)v;
    }
    float* BC = (float*)(ws + BIASC_OFF);        // biasC[l][n] = bih+bhh
    for (int i = idx; i < 5*512; i += stride) BC[i] = bih[i] + bhh[i];
}

// -------- main: persistent pipeline, MFMA core --------
__global__ void __launch_bounds__(512, 1)
lstm_main(const float* __restrict__ x_in, const float* __restrict__ Wih0,
          const float* __restrict__ W1,   const float* __restrict__ b1,
          const float* __restrict__ W2,   const float* __restrict__ b2,
          float* __restrict__ out, char* __restrict__ ws)
{
    __shared__ _Float16 A2[2][16][264];     // A operand dbuf: [m][k<128 own | k>=128 up]
    __shared__ float gatesF[4*16*132];      // [g][m][132pad r]; FC aliases zbsT/z2F here
    __shared__ float biasL[512];            // [g*128+r]
    __shared__ f4 wx4[128];                 // l0: Wih0 per-r (i,f,g,o)
    __shared__ float xcur[2][16];           // l0: x[t] per batch, dbuf

    const int tid  = threadIdx.x;
    const int lane = tid & 63;
    const int w    = tid >> 6;              // wave 0..7, owns ntiles 4w..4w+3
    const int col  = lane & 15, quad = lane >> 4;
    const int p = blockIdx.x / 5, l = blockIdx.x % 5;
    const bool isProd = (l < 4), isCons = (l > 0);
    const int um = tid >> 5, ur0 = (tid & 31) * 4;   // update cell map: (m, r0..r0+3)

    int*   flagL  = (int*)(ws + FLAGL_OFF);
    int*   fcflagP= (int*)(ws + FCFLAG_OFF) + p*64;
    float* fcoutG = (float*)(ws + FCOUT_OFF);
    _Float16* ringH = (_Float16*)(ws + RING_OFF);
    const _Float16* WcatG = (const _Float16*)(ws + WCAT_OFF) + l*512*256;
    const float* BC = (const float*)(ws + BIASC_OFF);

    int* upflag = flagL + (p*5 + (l > 0 ? l-1 : 0))*64;
    int* dnflag = flagL + (p*5 + (l < 4 ? l+1 : 4))*64;
    int* myflag = flagL + (p*5 + l)*64;
    _Float16* upRingH = ringH + (p*4 + (l > 0 ? l-1 : 0))*RING*2048;
    _Float16* myRingH = ringH + (p*4 + (l < 4 ? l   : 0))*RING*2048;

    // ---- B-fragments: permanently register-resident weights ----
    // bf[q][kt]: lane holds Wcat[nt*16+col][kt*32+quad*8 .. +8], nt = w*4+q
    v8h bf[4][8];
#pragma unroll
    for (int q = 0; q < 4; ++q)
#pragma unroll
        for (int kt = 0; kt < 8; ++kt)
            bf[q][kt] = *(const v8h*)&WcatG[((w*4+q)*16 + col)*256 + kt*32 + quad*8];

    // ---- LDS init ----
    for (int i = tid; i < 2*16*264; i += 512) ((_Float16*)A2)[i] = (_Float16)0.f;
    biasL[tid] = BC[l*512 + tid];
    if (l == 0 && tid < 128) {
        f4 v; v.x = Wih0[tid]; v.y = Wih0[128+tid]; v.z = Wih0[256+tid]; v.w = Wih0[384+tid];
        wx4[tid] = v;
    }
    if (l == 0 && tid < 16) xcur[0][tid] = x_in[(p*16 + tid)*512];

    int lastup = 0, lastdn = 0, lastfc = 0;
    if (isCons) {                      // pre-loop: fetch up-h(0) into A2[0] up-region
        int g = 0;
        while (lastup < 1) { if (++g > GUARD) break; lastup = LD(upflag); }
        unsigned long long r0 = LD64(&upRingH[(0*16 + um)*128 + ur0]);
        HU u; u.u = r0;
        *(h4v*)&A2[0][um][128 + ur0] = u.v;
    }
    __syncthreads();

    float c[4] = {0.f, 0.f, 0.f, 0.f};

    for (int t = 0; t < 514; ++t) {
        // ================= prep =================
        if (t < TAIL && (t & 3) == 0 && t > 0) {   // chunk boundary: drain+publish
            drain_vm();
            bar_lgkm();
            if (tid == 0) ST(myflag, t);
        }
        unsigned long long rv = 0;
        if (isCons && t + 1 < 514) {               // fetch up-h(t+1), latency hidden
            if (lastup < t + 2) {
                int g = 0;
                while (lastup < t + 2) { if (++g > GUARD) break; lastup = LD(upflag); }
            }
            rv = LD64(&upRingH[(((t+1) & (RING-1))*16 + um)*128 + ur0]);
        }
        float xnext = 0.f; bool hx = false;
        if (l == 0 && t + 1 < 512) {
            if (tid < 16) { xnext = x_in[(p*16 + tid)*512 + (t+1)]; hx = true; }
        } else if (l == 0 && t + 1 < 514) {        // autoregressive feedback
            int need = t - 510, g = 0;
            while (lastfc < need) { if (++g > GUARD) break; lastfc = LD(fcflagP); }
            if (tid < 16) { xnext = LD(&fcoutG[(p*2 + (t-511))*16 + tid]); hx = true; }
        }
        if (isProd && t >= RING && lastdn < t - 15) {   // ring backpressure (rare)
            int g = 0;
            while (lastdn < t - 15) { if (++g > GUARD) break; lastdn = LD(dnflag); }
        }

        // ================= MFMA: gates = A @ Wcat^T =================
        const _Float16* Ac = &A2[t & 1][0][0];
        f4 acc[4];
#pragma unroll
        for (int q = 0; q < 4; ++q) acc[q] = (f4){0.f, 0.f, 0.f, 0.f};
        v8h af[8];
#pragma unroll
        for (int kt = 0; kt < 8; ++kt)
            af[kt] = *(const v8h*)(Ac + col*264 + kt*32 + quad*8);
#pragma unroll
        for (int kt = 0; kt < 8; ++kt)
#pragma unroll
            for (int q = 0; q < 4; ++q)
                acc[q] = __builtin_amdgcn_mfma_f32_16x16x32_f16(af[kt], bf[q][kt], acc[q], 0, 0, 0);
#pragma unroll
        for (int q = 0; q < 4; ++q) {
            const int ng = (w*4 + q)*16 + col, gg = ng >> 7, rr = ng & 127;
#pragma unroll
            for (int i = 0; i < 4; ++i)
                gatesF[gg*2112 + (quad*4 + i)*132 + rr] = acc[q][i];
        }
        bar_lgkm();

        // ================= cell update: all 512 threads, 4 cells each =============
        f4 gv0 = *(const f4*)&gatesF[0*2112 + um*132 + ur0];
        f4 gv1 = *(const f4*)&gatesF[1*2112 + um*132 + ur0];
        f4 gv2 = *(const f4*)&gatesF[2*2112 + um*132 + ur0];
        f4 gv3 = *(const f4*)&gatesF[3*2112 + um*132 + ur0];
        f4 bv0 = *(const f4*)&biasL[0*128 + ur0];
        f4 bv1 = *(const f4*)&biasL[1*128 + ur0];
        f4 bv2 = *(const f4*)&biasL[2*128 + ur0];
        f4 bv3 = *(const f4*)&biasL[3*128 + ur0];
        float xt = xcur[t & 1][um];
        float hv[4];
#pragma unroll
        for (int i = 0; i < 4; ++i) {
            float gi = bv0[i] + gv0[i], gf = bv1[i] + gv1[i];
            float gG = bv2[i] + gv2[i], gO = bv3[i] + gv3[i];
            if (l == 0) {
                f4 wv = wx4[ur0 + i];
                gi = fmaf(wv.x, xt, gi); gf = fmaf(wv.y, xt, gf);
                gG = fmaf(wv.z, xt, gG); gO = fmaf(wv.w, xt, gO);
            }
            float si = sigm(gi), sf = sigm(gf), gt = tanh_f(gG), so = sigm(gO);
            c[i] = fmaf(sf, c[i], si * gt);
            hv[i] = so * tanh_f(c[i]);
        }
        h4v hp;
#pragma unroll
        for (int i = 0; i < 4; ++i) hp[i] = (_Float16)hv[i];
        *(h4v*)&A2[(t+1) & 1][um][ur0] = hp;               // own-h for step t+1
        if (isProd) {                                       // per-step sc1 ring store
            HU u; u.v = hp;
            ST64(&myRingH[((t & (RING-1))*16 + um)*128 + ur0], u.u);
        }
        if (isCons && t + 1 < 514) {                        // up-h(t+1) into A-next
            HU u; u.u = rv;
            *(h4v*)&A2[(t+1) & 1][um][128 + ur0] = u.v;
        }
        if (hx) xcur[(t+1) & 1][tid] = xnext;

        // ================= FC head (l==4, t>=511; 3x) =================
        if (l == 4 && t >= 511) {
            const int iter = t - 511;
            float* zbsT = gatesF;           // [k][18] pad — safe: gates already read
            float* z2F  = gatesF + 2304;    // [m][132]
            bar_lgkm();                     // all gate reads done before alias write
#pragma unroll
            for (int i = 0; i < 4; ++i) zbsT[(ur0 + i)*18 + um] = fmaxf(hv[i], 0.f);
            bar_lgkm();
            {
                const int o = tid & 127, mq = tid >> 7;     // mq wave-uniform
                float a0 = b1[o], a1 = b1[o], a2 = b1[o], a3 = b1[o];
#pragma unroll 8
                for (int k = 0; k < 128; ++k) {
                    float w1v = W1[k*128 + o];
                    const float* zr = &zbsT[k*18 + mq*4];
                    a0 = fmaf(zr[0], w1v, a0); a1 = fmaf(zr[1], w1v, a1);
                    a2 = fmaf(zr[2], w1v, a2); a3 = fmaf(zr[3], w1v, a3);
                }
                z2F[(mq*4+0)*132 + o] = fmaxf(a0, 0.f);
                z2F[(mq*4+1)*132 + o] = fmaxf(a1, 0.f);
                z2F[(mq*4+2)*132 + o] = fmaxf(a2, 0.f);
                z2F[(mq*4+3)*132 + o] = fmaxf(a3, 0.f);
            }
            bar_lgkm();
            if (tid < 256) {
                const int m = tid >> 4, o = tid & 15;
                float acc2 = b2[o];
#pragma unroll 8
                for (int k = 0; k < 128; ++k)
                    acc2 = fmaf(z2F[m*132 + k], W2[k*16 + o], acc2);
                if (iter == 2) {
                    out[(p*16 + m)*18 + 2 + o] = acc2;      // out2 full 16 cols
                } else if (o == 15) {
                    out[(p*16 + m)*18 + iter] = acc2;       // out_i[:,15]
                    ST(&fcoutG[(p*2 + iter)*16 + m], acc2);
                }
            }
            drain_vm();
            bar_lgkm();
            if (iter < 2 && tid == 0) ST(fcflagP, iter + 1);
        }

        // ================= end of step =================
        if (t >= TAIL) {
            drain_vm();                 // ring stores of this step at coherence point
            bar_lgkm();
            if (tid == 0) ST(myflag, t + 1);
        } else {
            bar_lgkm();
        }
    }
}

extern "C" void kernel_launch(void* const* d_in, const int* in_sizes, int n_in,
                              void* d_out, int out_size, void* d_ws, size_t ws_size,
                              hipStream_t stream) {
    (void)in_sizes; (void)n_in; (void)out_size; (void)ws_size;  // needs ~3.6MB ws
    const float* x    = (const float*)d_in[0];
    // d_in[1] = future (18, hardcoded)
    const float* Wih0 = (const float*)d_in[2];
    const float* WihR = (const float*)d_in[3];
    const float* Whh  = (const float*)d_in[4];
    const float* bihp = (const float*)d_in[5];
    const float* bhhp = (const float*)d_in[6];
    const float* W1   = (const float*)d_in[7];
    const float* b1   = (const float*)d_in[8];
    const float* W2   = (const float*)d_in[9];
    const float* b2   = (const float*)d_in[10];
    char* ws = (char*)d_ws;

    lstm_init<<<256, 256, 0, stream>>>(WihR, Whh, bihp, bhhp, ws);
    lstm_main<<<10, 512, 0, stream>>>(x, Wih0, W1, b1, W2, b2, (float*)d_out, ws);
}

// Round 10
// 1521.116 us; speedup vs baseline: 9.8295x; 9.8295x over previous
//
#include <hip/hip_runtime.h>

// LSTMPredictor: B=32,T=512,H=128,L=5,IN=1,OUT=16,future=18 -> one 514-step scan.
// R10 = R9 MFMA core + two fixes:
//  (1) REGISTER BUDGET VIA LDS: decoded default cap = 65536/threads (2 blocks/CU assumed).
//      Declaring >80KiB LDS makes 2 blocks/CU impossible -> 8 waves/CU -> 2 waves/EU
//      -> 256-reg budget. bf[4][8] (128 VGPRs of f16 weights) finally register-resident.
//  (2) TAIL DEADLOCK FIX: R9's prefetch (needs upstream t+2) was CIRCULAR with the
//      autoregressive feedback (l0@512 <- l4@511 <- l3@512 <- l2@513 <- l1@514 <- l0@514);
//      only GUARD expiries (16ms each) un-stuck it. Tail now current-fetches (needs t+1,
//      acyclic) and the fc-wait moved into the update phase.

typedef _Float16 v8h __attribute__((ext_vector_type(8)));
typedef _Float16 h4v __attribute__((ext_vector_type(4)));
typedef float f4 __attribute__((ext_vector_type(4)));

#define RING 16
#define TAIL 500
#define GUARD (1<<16)

#define FLAGL_OFF   0                 // int flagL[2*5][64]
#define FCFLAG_OFF  (64*1024)        // int fcflag[2][64]
#define FCOUT_OFF   (128*1024)       // float fcout[2][2][16]
#define RING_OFF    (256*1024)       // f16 ring[8 edges][16 slots][16 m][128 r] = 512KB
#define WCAT_OFF    (2*1024*1024)    // f16 Wcat[5][512][256] = 1.25MB
#define BIASC_OFF   (3*1024*1024 + 512*1024)  // float biasC[5][512]

#define AGENT __HIP_MEMORY_SCOPE_AGENT
#define LD(p)    __hip_atomic_load((p),  __ATOMIC_RELAXED, AGENT)
#define ST(p,v)  __hip_atomic_store((p), (v), __ATOMIC_RELAXED, AGENT)
#define LD64(p)  __hip_atomic_load((const unsigned long long*)(p), __ATOMIC_RELAXED, AGENT)
#define ST64(p,v) __hip_atomic_store((unsigned long long*)(p), (v), __ATOMIC_RELAXED, AGENT)

union HU { unsigned long long u; h4v v; };

__device__ __forceinline__ void bar_lgkm() {
    asm volatile("s_waitcnt lgkmcnt(0)\n\ts_barrier" ::: "memory");
}
__device__ __forceinline__ void drain_vm() {
    asm volatile("s_waitcnt vmcnt(0)" ::: "memory");
}
__device__ __forceinline__ float sigm(float x)   { return 1.f / (1.f + __expf(-x)); }
__device__ __forceinline__ float tanh_f(float x) { return 2.f / (1.f + __expf(-2.f * x)) - 1.f; }

// -------- init: zero flags, build Wcat f16 [5][512][256] and biasC --------
__global__ void lstm_init(const float* __restrict__ WihR, const float* __restrict__ Whh,
                          const float* __restrict__ bih,  const float* __restrict__ bhh,
                          char* __restrict__ ws)
{
    int idx = blockIdx.x * blockDim.x + threadIdx.x;
    int stride = gridDim.x * blockDim.x;
    int* wsi = (int*)ws;
    for (int i = idx; i < 65536; i += stride) wsi[i] = 0;   // flags + fcout (256KB)

    _Float16* WC = (_Float16*)(ws + WCAT_OFF);   // Wcat[l][n][k]: k<128 Whh, k>=128 Wih
    for (int i = idx; i < 5*512*256; i += stride) {
        int k = i & 255, n = (i >> 8) & 511, l = i >> 17;
        float v = (k < 128) ? Whh[(l*512 + n)*128 + k]
                            : (l > 0 ? WihR[((l-1)*512 + n)*128 + (k-128)] : 0.f);
        WC[i] = (_Float16)v;
    }
    float* BC = (float*)(ws + BIASC_OFF);        // biasC[l][n] = bih+bhh
    for (int i = idx; i < 5*512; i += stride) BC[i] = bih[i] + bhh[i];
}

// -------- main: persistent pipeline, MFMA core --------
__global__ void __launch_bounds__(512)
lstm_main(const float* __restrict__ x_in, const float* __restrict__ Wih0,
          const float* __restrict__ W1,   const float* __restrict__ b1,
          const float* __restrict__ W2,   const float* __restrict__ b2,
          float* __restrict__ out, char* __restrict__ ws)
{
    __shared__ _Float16 A2[2][16][264];     // A operand dbuf: [m][k<128 own | k>=128 up]
    __shared__ float gatesF[4*16*132];      // [g][m][132pad r]; FC aliases zbsT/z2F here
    __shared__ float biasL[512];            // [g*128+r]
    __shared__ f4 wx4[128];                 // l0: Wih0 per-r (i,f,g,o)
    __shared__ float occupancy_pad[8192];   // 32KB dead pad: total LDS ~87.5KB > 80KB
                                            // -> 1 block/CU -> 2 waves/EU -> 256-reg budget

    const int tid  = threadIdx.x;
    const int lane = tid & 63;
    const int w    = tid >> 6;              // wave 0..7, owns ntiles 4w..4w+3
    const int col  = lane & 15, quad = lane >> 4;
    const int p = blockIdx.x / 5, l = blockIdx.x % 5;
    const bool isProd = (l < 4), isCons = (l > 0);
    const int um = tid >> 5, ur0 = (tid & 31) * 4;   // update cell map: (m, r0..r0+3)

    int*   flagL  = (int*)(ws + FLAGL_OFF);
    int*   fcflagP= (int*)(ws + FCFLAG_OFF) + p*64;
    float* fcoutG = (float*)(ws + FCOUT_OFF);
    _Float16* ringH = (_Float16*)(ws + RING_OFF);
    const _Float16* WcatG = (const _Float16*)(ws + WCAT_OFF) + l*512*256;
    const float* BC = (const float*)(ws + BIASC_OFF);

    int* upflag = flagL + (p*5 + (l > 0 ? l-1 : 0))*64;
    int* dnflag = flagL + (p*5 + (l < 4 ? l+1 : 4))*64;
    int* myflag = flagL + (p*5 + l)*64;
    _Float16* upRingH = ringH + (p*4 + (l > 0 ? l-1 : 0))*RING*2048;
    _Float16* myRingH = ringH + (p*4 + (l < 4 ? l   : 0))*RING*2048;

    // keep the pad resident (volatile store cannot be elided)
    if (tid == 0) { volatile float* pv = occupancy_pad; pv[0] = 0.f; }

    // ---- B-fragments: permanently register-resident weights (128 VGPRs) ----
    v8h bf[4][8];
#pragma unroll
    for (int q = 0; q < 4; ++q)
#pragma unroll
        for (int kt = 0; kt < 8; ++kt)
            bf[q][kt] = *(const v8h*)&WcatG[((w*4+q)*16 + col)*256 + kt*32 + quad*8];

    // ---- LDS init ----
    for (int i = tid; i < 2*16*264; i += 512) ((_Float16*)A2)[i] = (_Float16)0.f;
    biasL[tid] = BC[l*512 + tid];
    if (l == 0 && tid < 128) {
        f4 v; v.x = Wih0[tid]; v.y = Wih0[128+tid]; v.z = Wih0[256+tid]; v.w = Wih0[384+tid];
        wx4[tid] = v;
    }

    int lastup = 0, lastdn = 0, lastfc = 0;
    if (isCons) {                      // pre-loop: fetch up-h(0) into A2[0] up-region
        int g = 0;
        while (lastup < 1) { if (++g > GUARD) break; lastup = LD(upflag); }
        unsigned long long r0 = LD64(&upRingH[(0*16 + um)*128 + ur0]);
        HU u; u.u = r0;
        *(h4v*)&A2[0][um][128 + ur0] = u.v;
    }
    __syncthreads();

    float c[4] = {0.f, 0.f, 0.f, 0.f};

    for (int t = 0; t < 514; ++t) {
        // ================= prep =================
        if (t > 0 && t <= TAIL && (t & 3) == 0) {   // chunk boundary: drain+publish
            drain_vm();
            bar_lgkm();
            if (tid == 0) ST(myflag, t);            // steps < t done & visible
        }
        unsigned long long rv = 0;
        if (isCons && t + 1 < TAIL) {               // steady-state prefetch of up-h(t+1)
            if (lastup < t + 2) {
                int g = 0;
                while (lastup < t + 2) { if (++g > GUARD) break; lastup = LD(upflag); }
            }
            rv = LD64(&upRingH[(((t+1) & (RING-1))*16 + um)*128 + ur0]);
        }
        if (isCons && t >= TAIL) {                  // tail: CURRENT fetch (needs t+1 only)
            if (lastup < t + 1) {
                int g = 0;
                while (lastup < t + 1) { if (++g > GUARD) break; lastup = LD(upflag); }
            }
            HU u; u.u = LD64(&upRingH[((t & (RING-1))*16 + um)*128 + ur0]);
            *(h4v*)&A2[t & 1][um][128 + ur0] = u.v;
        }
        float xtr = 0.f;
        if (l == 0 && t < 512) xtr = x_in[(p*16 + um)*512 + t];   // per-thread x prefetch
        if (isProd && t >= RING && lastdn < t - 15) {   // ring backpressure (rare)
            int g = 0;
            while (lastdn < t - 15) { if (++g > GUARD) break; lastdn = LD(dnflag); }
        }
        if (isCons && t >= TAIL) bar_lgkm();        // tail-fetch A2 write visible (WG-uniform)

        // ================= MFMA: gates = A @ Wcat^T =================
        const _Float16* Ac = &A2[t & 1][0][0];
        f4 acc[4];
#pragma unroll
        for (int q = 0; q < 4; ++q) acc[q] = (f4){0.f, 0.f, 0.f, 0.f};
        v8h af[8];
#pragma unroll
        for (int kt = 0; kt < 8; ++kt)
            af[kt] = *(const v8h*)(Ac + col*264 + kt*32 + quad*8);
#pragma unroll
        for (int kt = 0; kt < 8; ++kt)
#pragma unroll
            for (int q = 0; q < 4; ++q)
                acc[q] = __builtin_amdgcn_mfma_f32_16x16x32_f16(af[kt], bf[q][kt], acc[q], 0, 0, 0);
#pragma unroll
        for (int q = 0; q < 4; ++q) {
            const int ng = (w*4 + q)*16 + col, gg = ng >> 7, rr = ng & 127;
#pragma unroll
            for (int i = 0; i < 4; ++i)
                gatesF[gg*2112 + (quad*4 + i)*132 + rr] = acc[q][i];
        }
        bar_lgkm();

        // ================= cell update: all 512 threads, 4 cells each =============
        float xt = 0.f;
        if (l == 0) {
            if (t < 512) xt = xtr;
            else {                                   // feedback wait HERE (acyclic)
                int need = t - 511, g = 0;
                while (lastfc < need) { if (++g > GUARD) break; lastfc = LD(fcflagP); }
                xt = LD(&fcoutG[(p*2 + (t - 512))*16 + um]);
            }
        }
        f4 gv0 = *(const f4*)&gatesF[0*2112 + um*132 + ur0];
        f4 gv1 = *(const f4*)&gatesF[1*2112 + um*132 + ur0];
        f4 gv2 = *(const f4*)&gatesF[2*2112 + um*132 + ur0];
        f4 gv3 = *(const f4*)&gatesF[3*2112 + um*132 + ur0];
        f4 bv0 = *(const f4*)&biasL[0*128 + ur0];
        f4 bv1 = *(const f4*)&biasL[1*128 + ur0];
        f4 bv2 = *(const f4*)&biasL[2*128 + ur0];
        f4 bv3 = *(const f4*)&biasL[3*128 + ur0];
        float hv[4];
#pragma unroll
        for (int i = 0; i < 4; ++i) {
            float gi = bv0[i] + gv0[i], gf = bv1[i] + gv1[i];
            float gG = bv2[i] + gv2[i], gO = bv3[i] + gv3[i];
            if (l == 0) {
                f4 wv = wx4[ur0 + i];
                gi = fmaf(wv.x, xt, gi); gf = fmaf(wv.y, xt, gf);
                gG = fmaf(wv.z, xt, gG); gO = fmaf(wv.w, xt, gO);
            }
            float si = sigm(gi), sf = sigm(gf), gt = tanh_f(gG), so = sigm(gO);
            c[i] = fmaf(sf, c[i], si * gt);
            hv[i] = so * tanh_f(c[i]);
        }
        h4v hp;
#pragma unroll
        for (int i = 0; i < 4; ++i) hp[i] = (_Float16)hv[i];
        *(h4v*)&A2[(t+1) & 1][um][ur0] = hp;               // own-h for step t+1
        if (isProd) {                                       // per-step sc1 ring store
            HU u; u.v = hp;
            ST64(&myRingH[((t & (RING-1))*16 + um)*128 + ur0], u.u);
        }
        if (isCons && t + 1 < TAIL) {                       // prefetched up-h(t+1) -> A-next
            HU u; u.u = rv;
            *(h4v*)&A2[(t+1) & 1][um][128 + ur0] = u.v;
        }

        // ================= FC head (l==4, t>=511; 3x) =================
        if (l == 4 && t >= 511) {
            const int iter = t - 511;
            float* zbsT = gatesF;           // [k][18] pad — gates already consumed
            float* z2F  = gatesF + 2304;    // [m][132]
            bar_lgkm();                     // all gate reads done before alias write
#pragma unroll
            for (int i = 0; i < 4; ++i) zbsT[(ur0 + i)*18 + um] = fmaxf(hv[i], 0.f);
            bar_lgkm();
            {
                const int o = tid & 127, mq = tid >> 7;     // mq wave-uniform
                float a0 = b1[o], a1 = b1[o], a2 = b1[o], a3 = b1[o];
#pragma unroll 8
                for (int k = 0; k < 128; ++k) {
                    float w1v = W1[k*128 + o];
                    const float* zr = &zbsT[k*18 + mq*4];
                    a0 = fmaf(zr[0], w1v, a0); a1 = fmaf(zr[1], w1v, a1);
                    a2 = fmaf(zr[2], w1v, a2); a3 = fmaf(zr[3], w1v, a3);
                }
                z2F[(mq*4+0)*132 + o] = fmaxf(a0, 0.f);
                z2F[(mq*4+1)*132 + o] = fmaxf(a1, 0.f);
                z2F[(mq*4+2)*132 + o] = fmaxf(a2, 0.f);
                z2F[(mq*4+3)*132 + o] = fmaxf(a3, 0.f);
            }
            bar_lgkm();
            if (tid < 256) {
                const int m = tid >> 4, o = tid & 15;
                float acc2 = b2[o];
#pragma unroll 8
                for (int k = 0; k < 128; ++k)
                    acc2 = fmaf(z2F[m*132 + k], W2[k*16 + o], acc2);
                if (iter == 2) {
                    out[(p*16 + m)*18 + 2 + o] = acc2;      // out2 full 16 cols
                } else if (o == 15) {
                    out[(p*16 + m)*18 + iter] = acc2;       // out_i[:,15]
                    ST(&fcoutG[(p*2 + iter)*16 + m], acc2);
                }
            }
            drain_vm();                                     // fcout at coherence point
            bar_lgkm();
            if (iter < 2 && tid == 0) ST(fcflagP, iter + 1);
        }

        // ================= end of step =================
        if (t >= TAIL) {
            drain_vm();                 // this step's ring stores visible
            bar_lgkm();
            if (tid == 0) ST(myflag, t + 1);
        } else {
            bar_lgkm();
        }
    }
}

extern "C" void kernel_launch(void* const* d_in, const int* in_sizes, int n_in,
                              void* d_out, int out_size, void* d_ws, size_t ws_size,
                              hipStream_t stream) {
    (void)in_sizes; (void)n_in; (void)out_size; (void)ws_size;  // needs ~3.6MB ws
    const float* x    = (const float*)d_in[0];
    // d_in[1] = future (18, hardcoded)
    const float* Wih0 = (const float*)d_in[2];
    const float* WihR = (const float*)d_in[3];
    const float* Whh  = (const float*)d_in[4];
    const float* bihp = (const float*)d_in[5];
    const float* bhhp = (const float*)d_in[6];
    const float* W1   = (const float*)d_in[7];
    const float* b1   = (const float*)d_in[8];
    const float* W2   = (const float*)d_in[9];
    const float* b2   = (const float*)d_in[10];
    char* ws = (char*)d_ws;

    lstm_init<<<256, 256, 0, stream>>>(WihR, Whh, bihp, bhhp, ws);
    lstm_main<<<10, 512, 0, stream>>>(x, Wih0, W1, b1, W2, b2, (float*)d_out, ws);
}

// Round 11
// 1444.025 us; speedup vs baseline: 10.3542x; 1.0534x over previous
//
#include <hip/hip_runtime.h>

// LSTMPredictor: B=32,T=512,H=128,L=5,IN=1,OUT=16,future=18 -> one 514-step scan.
// R11: live under the (immovable) 128-reg/thread cap BY CONSTRUCTION:
//   - hh weight half (kt 0-3) in 64 VGPRs; ih half (kt 4-7) in LDS (128KB, copied once).
//   - wave w owns n-tiles {w, 8+w, 16+w, 24+w}: one lane's 4 MFMA accs = gates i,f,g,o of
//     cell (m=quad*4+i, r=16w+col) -> cell update IN-REGISTER; gatesF LDS round-trip and
//     one barrier per step deleted.
//   - transport = R10's verified protocol (chunked flags, per-step tail, acyclic feedback).
// 10 WGs = 5 layers x 2 batch-halves, 512 thr, ~157KB LDS -> 1 WG/CU.

typedef _Float16 v8h __attribute__((ext_vector_type(8)));
typedef _Float16 h4v __attribute__((ext_vector_type(4)));
typedef float f4 __attribute__((ext_vector_type(4)));

#define RING 16
#define TAIL 500
#define GUARD (1<<16)

#define FLAGL_OFF   0                 // int flagL[2*5][64]
#define FCFLAG_OFF  (64*1024)        // int fcflag[2][64]
#define FCOUT_OFF   (128*1024)       // float fcout[2][2][16]
#define RING_OFF    (256*1024)       // f16 ring[8][16][16][128] = 512KB
#define WCATR_OFF   (2*1024*1024)    // f16 WcatR[5][512][128] (hh) = 640KB
#define WL_OFF      (3*1024*1024)    // f16 WLg[5][16][512][8] (ih, ktq-major) = 640KB
#define BIASC_OFF   (4*1024*1024)    // f32 biasC[5][128][4]

#define AGENT __HIP_MEMORY_SCOPE_AGENT
#define LD(p)    __hip_atomic_load((p),  __ATOMIC_RELAXED, AGENT)
#define ST(p,v)  __hip_atomic_store((p), (v), __ATOMIC_RELAXED, AGENT)
#define LD64(p)  __hip_atomic_load((const unsigned long long*)(p), __ATOMIC_RELAXED, AGENT)
#define ST64(p,v) __hip_atomic_store((unsigned long long*)(p), (v), __ATOMIC_RELAXED, AGENT)

union HU { unsigned long long u; h4v v; };

__device__ __forceinline__ void bar_lgkm() {
    asm volatile("s_waitcnt lgkmcnt(0)\n\ts_barrier" ::: "memory");
}
__device__ __forceinline__ void drain_vm() {
    asm volatile("s_waitcnt vmcnt(0)" ::: "memory");
}
__device__ __forceinline__ float sigm(float x)   { return 1.f / (1.f + __expf(-x)); }
__device__ __forceinline__ float tanh_f(float x) { return 2.f / (1.f + __expf(-2.f * x)) - 1.f; }

// -------- init: flags=0, WcatR (hh f16), WLg (ih f16 ktq-major), biasC --------
__global__ void lstm_init(const float* __restrict__ WihR, const float* __restrict__ Whh,
                          const float* __restrict__ bih,  const float* __restrict__ bhh,
                          char* __restrict__ ws)
{
    int idx = blockIdx.x * blockDim.x + threadIdx.x;
    int stride = gridDim.x * blockDim.x;
    int* wsi = (int*)ws;
    for (int i = idx; i < 65536; i += stride) wsi[i] = 0;

    _Float16* WR = (_Float16*)(ws + WCATR_OFF);        // [l][n][k<128]
    for (int i = idx; i < 5*512*128; i += stride) {
        int k = i & 127, n = (i >> 7) & 511, l = i >> 16;
        WR[i] = (_Float16)Whh[(l*512 + n)*128 + k];
    }
    _Float16* WLp = (_Float16*)(ws + WL_OFF);          // [l][ktq][n][8]
    for (int i = idx; i < 5*16*512*8; i += stride) {
        int j = i & 7, n = (i >> 3) & 511, ktq = (i >> 12) & 15, l = i >> 16;
        int k = (ktq >> 2)*32 + (ktq & 3)*8 + j;       // ih column (0..127)
        WLp[i] = (_Float16)(l > 0 ? WihR[((l-1)*512 + n)*128 + k] : 0.f);
    }
    float* BC = (float*)(ws + BIASC_OFF);              // [l][r][g]
    for (int i = idx; i < 5*128*4; i += stride) {
        int g = i & 3, r = (i >> 2) & 127, l = i >> 9;
        BC[i] = bih[l*512 + g*128 + r] + bhh[l*512 + g*128 + r];
    }
}

// -------- main: persistent pipeline --------
__global__ void __launch_bounds__(512)
lstm_main(const float* __restrict__ x_in, const float* __restrict__ Wih0,
          const float* __restrict__ W1,   const float* __restrict__ b1,
          const float* __restrict__ W2,   const float* __restrict__ b2,
          float* __restrict__ out, char* __restrict__ ws)
{
    __shared__ __align__(16) _Float16 WL[16][512][8];   // 128KB: ih weights
    __shared__ __align__(16) _Float16 A2[2][16][264];   // 16.5KB: A dbuf [m][own|up]
    __shared__ float  fcb[2304];                        // 9.2KB: FC scratch (zbsT / z2F)
    __shared__ f4     biasL[128];                       // [r] = (bi,bf,bg,bo)
    __shared__ f4     wx4[128];                         // l0: Wih0 per r
    __shared__ float  xcur[2][16];                      // l0: x[t] dbuf

    const int tid  = threadIdx.x;
    const int lane = tid & 63;
    const int w    = tid >> 6;              // wave 0..7 -> n-tiles {w,8+w,16+w,24+w}
    const int col  = lane & 15, quad = lane >> 4;
    const int r    = w*16 + col;            // this lane's hidden row
    const int p = blockIdx.x / 5, l = blockIdx.x % 5;
    const bool isProd = (l < 4), isCons = (l > 0);
    const int tm = tid >> 5, tr0 = (tid & 31) * 4;   // transport map: (m, r0)

    int*   flagL  = (int*)(ws + FLAGL_OFF);
    int*   fcflagP= (int*)(ws + FCFLAG_OFF) + p*64;
    float* fcoutG = (float*)(ws + FCOUT_OFF);
    _Float16* ringH = (_Float16*)(ws + RING_OFF);
    const _Float16* WR  = (const _Float16*)(ws + WCATR_OFF) + l*512*128;
    const float4*   WLs = (const float4*)(ws + WL_OFF + (size_t)l*131072);

    int* upflag = flagL + (p*5 + (l > 0 ? l-1 : 0))*64;
    int* dnflag = flagL + (p*5 + (l < 4 ? l+1 : 4))*64;
    int* myflag = flagL + (p*5 + l)*64;
    _Float16* upRingH = ringH + (p*4 + (l > 0 ? l-1 : 0))*RING*2048;
    _Float16* myRingH = ringH + (p*4 + (l < 4 ? l   : 0))*RING*2048;

    // ---- hh weights: registers (64 VGPRs) ----
    v8h bf[4][4];
#pragma unroll
    for (int q = 0; q < 4; ++q)
#pragma unroll
        for (int kt = 0; kt < 4; ++kt)
            bf[q][kt] = *(const v8h*)&WR[((q*8 + w)*16 + col)*128 + kt*32 + quad*8];

    // ---- ih weights: copy to LDS (one time, 128KB) ----
    if (isCons) {
        for (int i = tid; i < 8192; i += 512)
            ((float4*)WL)[i] = WLs[i];
    }
    for (int i = tid; i < 8448; i += 512) ((_Float16*)A2)[i] = (_Float16)0.f;
    if (tid < 128) {
        biasL[tid] = ((const f4*)(ws + BIASC_OFF))[l*128 + tid];
        if (l == 0) {
            f4 v; v.x = Wih0[tid]; v.y = Wih0[128+tid]; v.z = Wih0[256+tid]; v.w = Wih0[384+tid];
            wx4[tid] = v;
        }
    }
    if (l == 0 && tid < 16) xcur[0][tid] = x_in[(p*16 + tid)*512];

    int lastup = 0, lastdn = 0, lastfc = 0;
    if (isCons) {                       // seed up-h(0)
        int g = 0;
        while (lastup < 1) { if (++g > GUARD) break; lastup = LD(upflag); }
        HU u; u.u = LD64(&upRingH[(0*16 + tm)*128 + tr0]);
        *(h4v*)&A2[0][tm][128 + tr0] = u.v;
    }
    __syncthreads();

    float c[4] = {0.f, 0.f, 0.f, 0.f};

    for (int t = 0; t < 514; ++t) {
        const int cur = t & 1, nxt = (t + 1) & 1;

        // ---- steady ring store of h(t-1) + chunk publish ----
        if (isProd && t > 0 && t <= TAIL) {
            HU u; u.v = *(const h4v*)&A2[cur][tm][tr0];
            ST64(&myRingH[(((t-1) & 15)*16 + tm)*128 + tr0], u.u);
        }
        if (t > 0 && t <= TAIL && (t & 3) == 0) {
            drain_vm();
            bar_lgkm();
            if (tid == 0) ST(myflag, t);
        }

        // ---- steady prefetch up-h(t+1) ----
        unsigned long long rv = 0;
        if (isCons && t + 1 < TAIL) {
            if (lastup < t + 2) {
                int g = 0;
                while (lastup < t + 2) { if (++g > GUARD) break; lastup = LD(upflag); }
            }
            rv = LD64(&upRingH[(((t+1) & 15)*16 + tm)*128 + tr0]);
        }
        // ---- tail current-fetch up-h(t) ----
        if (isCons && t >= TAIL) {
            if (lastup < t + 1) {
                int g = 0;
                while (lastup < t + 1) { if (++g > GUARD) break; lastup = LD(upflag); }
            }
            HU u; u.u = LD64(&upRingH[((t & 15)*16 + tm)*128 + tr0]);
            *(h4v*)&A2[cur][tm][128 + tr0] = u.v;
        }
        if (isCons && t >= TAIL) bar_lgkm();

        // ---- l0 x prefetch (steady) ----
        if (l == 0 && t + 1 < 512 && tid < 16)
            xcur[nxt][tid] = x_in[(p*16 + tid)*512 + (t+1)];
        // ---- backpressure (rare) ----
        if (isProd && t >= RING && lastdn < t - 15) {
            int g = 0;
            while (lastdn < t - 15) { if (++g > GUARD) break; lastdn = LD(dnflag); }
        }

        // ================= MFMA: gates = A @ [Whh | Wih]^T =================
        const _Float16* Ac = &A2[cur][0][0];
        f4 acc[4];
#pragma unroll
        for (int q = 0; q < 4; ++q) acc[q] = (f4){0.f, 0.f, 0.f, 0.f};
#pragma unroll
        for (int kt = 0; kt < 4; ++kt) {                 // hh: B from registers
            v8h af = *(const v8h*)(Ac + col*264 + kt*32 + quad*8);
#pragma unroll
            for (int q = 0; q < 4; ++q)
                acc[q] = __builtin_amdgcn_mfma_f32_16x16x32_f16(af, bf[q][kt], acc[q], 0, 0, 0);
        }
        if (isCons) {
#pragma unroll
            for (int kt = 4; kt < 8; ++kt) {             // ih: B from LDS
                v8h af = *(const v8h*)(Ac + col*264 + kt*32 + quad*8);
                const int ktq = (kt - 4)*4 + quad;
#pragma unroll
                for (int q = 0; q < 4; ++q) {
                    v8h wf = *(const v8h*)&WL[ktq][(q*8 + w)*16 + col][0];
                    acc[q] = __builtin_amdgcn_mfma_f32_16x16x32_f16(af, wf, acc[q], 0, 0, 0);
                }
            }
        }

        // ---- l0 tail: feedback x into xcur[cur] ----
        if (l == 0 && t >= 512) {
            if (tid < 16) {
                int need = t - 511, g = 0;
                while (lastfc < need) { if (++g > GUARD) break; lastfc = LD(fcflagP); }
                xcur[cur][tid] = LD(&fcoutG[(p*2 + (t - 512))*16 + tid]);
            }
            bar_lgkm();
        }

        // ================= cell update: IN-REGISTER (lane owns 4 cells) ==========
        f4 bv = biasL[r];
        f4 wxv; float xts[4];
        if (l == 0) {
            wxv = wx4[r];
#pragma unroll
            for (int i = 0; i < 4; ++i) xts[i] = xcur[cur][quad*4 + i];
        }
        float hv[4];
#pragma unroll
        for (int i = 0; i < 4; ++i) {
            float gi = acc[0][i] + bv.x, gf = acc[1][i] + bv.y;
            float gG = acc[2][i] + bv.z, gO = acc[3][i] + bv.w;
            if (l == 0) {
                gi = fmaf(wxv.x, xts[i], gi); gf = fmaf(wxv.y, xts[i], gf);
                gG = fmaf(wxv.z, xts[i], gG); gO = fmaf(wxv.w, xts[i], gO);
            }
            float si = sigm(gi), sf = sigm(gf), gt = tanh_f(gG), so = sigm(gO);
            c[i] = fmaf(sf, c[i], si * gt);
            hv[i] = so * tanh_f(c[i]);
            A2[nxt][quad*4 + i][r] = (_Float16)hv[i];    // own-h(t) for step t+1
        }
        if (isCons && t + 1 < TAIL) {                    // prefetched up-h(t+1)
            HU u; u.u = rv;
            *(h4v*)&A2[nxt][tm][128 + tr0] = u.v;
        }
        bar_lgkm();

        // ---- tail: store h(t) + per-step publish ----
        if (isProd && t >= TAIL) {
            HU u; u.v = *(const h4v*)&A2[nxt][tm][tr0];
            ST64(&myRingH[((t & 15)*16 + tm)*128 + tr0], u.u);
            drain_vm();
            bar_lgkm();
            if (tid == 0) ST(myflag, t + 1);
        }

        // ================= FC head (l==4, t>=511; 3x) =================
        if (l == 4 && t >= 511) {
            const int iter = t - 511;
#pragma unroll
            for (int i = 0; i < 4; ++i)                  // zbsT[k][m] (f32, from regs)
                fcb[r*18 + quad*4 + i] = fmaxf(hv[i], 0.f);
            bar_lgkm();
            const int o = tid & 127, mq = tid >> 7;      // FC1: 512 thr, 4 m each
            float a0 = b1[o], a1 = a0, a2 = a0, a3 = a0;
#pragma unroll 8
            for (int k = 0; k < 128; ++k) {
                float w1v = W1[k*128 + o];
                const float* zr = &fcb[k*18 + mq*4];
                a0 = fmaf(zr[0], w1v, a0); a1 = fmaf(zr[1], w1v, a1);
                a2 = fmaf(zr[2], w1v, a2); a3 = fmaf(zr[3], w1v, a3);
            }
            bar_lgkm();                                  // all zbsT reads done
            fcb[(mq*4+0)*132 + o] = fmaxf(a0, 0.f);      // z2F[m][132]
            fcb[(mq*4+1)*132 + o] = fmaxf(a1, 0.f);
            fcb[(mq*4+2)*132 + o] = fmaxf(a2, 0.f);
            fcb[(mq*4+3)*132 + o] = fmaxf(a3, 0.f);
            bar_lgkm();
            if (tid < 256) {
                const int m = tid >> 4, oo = tid & 15;
                float acc2 = b2[oo];
#pragma unroll 8
                for (int k = 0; k < 128; ++k)
                    acc2 = fmaf(fcb[m*132 + k], W2[k*16 + oo], acc2);
                if (iter == 2) {
                    out[(p*16 + m)*18 + 2 + oo] = acc2;
                } else if (oo == 15) {
                    out[(p*16 + m)*18 + iter] = acc2;
                    ST(&fcoutG[(p*2 + iter)*16 + m], acc2);
                }
            }
            drain_vm();
            bar_lgkm();
            if (iter < 2 && tid == 0) ST(fcflagP, iter + 1);
        }
    }
}

extern "C" void kernel_launch(void* const* d_in, const int* in_sizes, int n_in,
                              void* d_out, int out_size, void* d_ws, size_t ws_size,
                              hipStream_t stream) {
    (void)in_sizes; (void)n_in; (void)out_size; (void)ws_size;  // needs ~4.1MB ws
    const float* x    = (const float*)d_in[0];
    // d_in[1] = future (18, hardcoded)
    const float* Wih0 = (const float*)d_in[2];
    const float* WihR = (const float*)d_in[3];
    const float* Whh  = (const float*)d_in[4];
    const float* bihp = (const float*)d_in[5];
    const float* bhhp = (const float*)d_in[6];
    const float* W1   = (const float*)d_in[7];
    const float* b1   = (const float*)d_in[8];
    const float* W2   = (const float*)d_in[9];
    const float* b2   = (const float*)d_in[10];
    char* ws = (char*)d_ws;

    lstm_init<<<256, 256, 0, stream>>>(WihR, Whh, bihp, bhhp, ws);
    lstm_main<<<10, 512, 0, stream>>>(x, Wih0, W1, b1, W2, b2, (float*)d_out, ws);
}